// Round 14
// baseline (439.733 us; speedup 1.0000x reference)
//
#include <hip/hip_runtime.h>

#define TOK 4096
#define HD 1024
#define ID 4096
#define NE 8
#define MAXT 40   // max m-tiles: sum ceil(ne/128) <= 32 + 8

typedef __attribute__((ext_vector_type(4))) float f32x4;
typedef __attribute__((ext_vector_type(8))) __bf16 bf16x8;
typedef __attribute__((ext_vector_type(8))) unsigned short u16x8;

// LDS rows are 128B (BK=64 bf16) = 8 x 16B slots; swizzle slot s -> s ^ (row&7).
// Reads: 16 consecutive rows x 4 fk-slots spread evenly over all 8 slot groups.
#define SW8(r, s) ((((s) ^ ((r) & 7))) << 4)

// compiler emits v_cvt_pk_bf16_f32 (RNE) for scalar casts -- do NOT hand-roll (m240)
__device__ __forceinline__ bf16x8 pack8(f32x4 a, f32x4 b) {
  bf16x8 r;
#pragma unroll
  for (int i = 0; i < 4; ++i) { r[i] = (__bf16)a[i]; r[i + 4] = (__bf16)b[i]; }
  return r;
}

__device__ __forceinline__ float gelu_tanh(float g) {
  float z = 0.7978845608028654f * (g + 0.044715f * g * g * g);
  float t = __expf(-2.0f * z);
  return g / (1.0f + t);
}

// barrier that does NOT drain vmcnt: LDS ordering via lgkmcnt(0), global prefetch stays in flight
__device__ __forceinline__ void bar_lgkm() {
  asm volatile("s_waitcnt lgkmcnt(0)" ::: "memory");
  __builtin_amdgcn_s_barrier();
}

__global__ void init_k(int* __restrict__ meta) {
  if (threadIdx.x < 16) meta[threadIdx.x] = 0;
}

// one wave per token: fp32 logits (argmax must match numpy fp32), top1 via first-max
__global__ void router_k(const float* __restrict__ x, const float* __restrict__ gw,
                         float* __restrict__ logits, int* __restrict__ top1) {
  const int wid = threadIdx.x >> 6;
  const int lane = threadIdx.x & 63;
  const int t = blockIdx.x * 4 + wid;
  const float* xr = x + (size_t)t * HD;
  float acc[NE];
#pragma unroll
  for (int e = 0; e < NE; ++e) acc[e] = 0.0f;
#pragma unroll
  for (int c = 0; c < 4; ++c) {
    const int k = (c * 64 + lane) * 4;
    f32x4 xv = *(const f32x4*)(xr + k);
#pragma unroll
    for (int e = 0; e < NE; ++e) {
      f32x4 gv = *(const f32x4*)(gw + e * HD + k);
      acc[e] += xv[0] * gv[0] + xv[1] * gv[1] + xv[2] * gv[2] + xv[3] * gv[3];
    }
  }
#pragma unroll
  for (int off = 32; off > 0; off >>= 1) {
#pragma unroll
    for (int e = 0; e < NE; ++e) acc[e] += __shfl_xor(acc[e], off, 64);
  }
  if (lane == 0) {
    int best = 0; float bv = acc[0];
#pragma unroll
    for (int e = 1; e < NE; ++e) if (acc[e] > bv) { bv = acc[e]; best = e; }
    top1[t] = best;
#pragma unroll
    for (int e = 0; e < NE; ++e) logits[(size_t)t * NE + e] = acc[e];
  }
}

__global__ void hist_k(const int* __restrict__ top1, int* __restrict__ counts) {
  int t = blockIdx.x * 256 + threadIdx.x;
  atomicAdd(&counts[top1[t]], 1);
}

// offsets + compacted tile map: tilemap[t] = (e<<8)|mt for every REAL m-tile
__global__ void offsets_k(const int* __restrict__ counts, int* __restrict__ offsets,
                          int* __restrict__ tilemap, int* __restrict__ ntiles) {
  if (threadIdx.x == 0) {
    int s = 0;
    for (int e = 0; e < NE; ++e) { offsets[e] = s; s += counts[e]; }
    int t = 0;
    for (int e = 0; e < NE; ++e) {
      int nt_e = (counts[e] + 127) >> 7;
      for (int i = 0; i < nt_e; ++i) tilemap[t++] = (e << 8) | i;
    }
    *ntiles = t;
  }
}

__global__ void scatter_k(const int* __restrict__ top1, const int* __restrict__ offsets,
                          int* __restrict__ counts2, int* __restrict__ perm) {
  int t = blockIdx.x * 256 + threadIdx.x;
  int e = top1[t];
  int slot = atomicAdd(&counts2[e], 1);
  perm[offsets[e] + slot] = t;
}

// compact permuted bf16 copy of x: xp[p,:] = bf16(x[perm[p],:])
__global__ void xp_k(const float* __restrict__ x, const int* __restrict__ perm,
                     unsigned short* __restrict__ xp) {
  const int p = blockIdx.x * 4 + (threadIdx.x >> 6);
  const int lane = threadIdx.x & 63;
  const float* src = x + (size_t)perm[p] * HD + lane * 16;
  unsigned short* dst = xp + (size_t)p * HD + lane * 16;
  f32x4 v0 = *(const f32x4*)(src);
  f32x4 v1 = *(const f32x4*)(src + 4);
  f32x4 v2 = *(const f32x4*)(src + 8);
  f32x4 v3 = *(const f32x4*)(src + 12);
  *(bf16x8*)(dst) = pack8(v0, v1);
  *(bf16x8*)(dst + 8) = pack8(v2, v3);
}

// gemm1: BM=128 tok x BN=128 (64 gate || 64 up cols of panel nt), BK=64.
// 256 thr / 4 waves = 2wm x 2role, wave 64x64 (acc 4x4). dbuf LDS (A 2x16K, B 2x16K),
// ONE lgkm-barrier per K-tile (dbuf: RAW and WAR both drain at the same lgkm(0)+bar),
// depth-2 register tile prefetch (loads for t+2 in flight across 2 barriers).
// Gate/up fused via f32 LDS exchange epilogue.
__global__ __launch_bounds__(256, 2) void gemm1_k(
    const unsigned short* __restrict__ xp, const float* __restrict__ wg,
    const float* __restrict__ wu, const int* __restrict__ counts,
    const int* __restrict__ offsets, const int* __restrict__ tilemap,
    const int* __restrict__ ntiles, unsigned short* __restrict__ hidden) {
  const int t = blockIdx.x >> 6;
  const int nt = blockIdx.x & 63;          // 64 panels of 64 out-cols; siblings bid+=64 -> same XCD
  if (t >= *ntiles) return;
  const int tm = tilemap[t];
  const int e = tm >> 8, mt = tm & 255;
  const int ne = counts[e];
  const int off = offsets[e];

  __shared__ __align__(16) char lds[65536];  // A: p*16384; B: 32768 + p*16384; exch f32 [128][68]

  const int tid = threadIdx.x;
  const int lane = tid & 63;
  const int wid = tid >> 6;
  const int wm = wid >> 1;                 // 0..1 -> rows wm*64
  const int role = wid & 1;                // 0 = gate, 1 = up
  const int wrow = wm * 64;
  const int brow0 = role * 64;
  const int frow = lane & 15;
  const int fk = lane >> 4;                // 0..3

  // A staging: 2 thr/row, 32 bf16 (64B) each. row=tid>>1, half=tid&1 -> slots h*4+0..3
  const int ar = tid >> 1, ah = tid & 1;
  int tokrow = off + mt * 128 + ar;
  if (tokrow >= TOK) tokrow = TOK - 1;     // masked at store
  const unsigned short* asrc = xp + (size_t)tokrow * HD + ah * 32;

  // B staging: 2 thr/row, 32 fp32 (128B) each. rows 0-63 gate, 64-127 up
  const int br = tid >> 1, bh = tid & 1;
  const float* bsrc = (br < 64)
      ? wg + ((size_t)e * ID + nt * 64 + br) * HD + bh * 32
      : wu + ((size_t)e * ID + nt * 64 + (br - 64)) * HD + bh * 32;

  f32x4 acc[4][4] = {};
  u16x8 rA[2][4];
  f32x4 rB[2][8];

#define G1_LOAD(kt, q)                                                    \
  do {                                                                    \
    const unsigned short* a_ = asrc + (kt) * 64;                          \
    _Pragma("unroll") for (int i = 0; i < 4; ++i)                         \
      rA[q][i] = *(const u16x8*)(a_ + i * 8);                             \
    const float* b_ = bsrc + (kt) * 64;                                   \
    _Pragma("unroll") for (int i = 0; i < 8; ++i)                         \
      rB[q][i] = *(const f32x4*)(b_ + i * 4);                             \
  } while (0)

#define G1_WRITE(P, q)                                                    \
  do {                                                                    \
    _Pragma("unroll") for (int i = 0; i < 4; ++i)                         \
      *(u16x8*)(lds + (P) * 16384 + ar * 128 + SW8(ar, ah * 4 + i)) = rA[q][i]; \
    _Pragma("unroll") for (int i = 0; i < 4; ++i)                         \
      *(bf16x8*)(lds + 32768 + (P) * 16384 + br * 128 + SW8(br, bh * 4 + i)) = \
          pack8(rB[q][2 * i], rB[q][2 * i + 1]);                          \
  } while (0)

#define G1_READS(P, H, AF, BF)                                            \
  do {                                                                    \
    _Pragma("unroll") for (int mi = 0; mi < 4; ++mi) {                    \
      const int r_ = wrow + mi * 16 + frow;                               \
      AF[mi] = *(const bf16x8*)(lds + (P) * 16384 + r_ * 128 + SW8(r_, (H) * 4 + fk)); \
    }                                                                     \
    _Pragma("unroll") for (int ni = 0; ni < 4; ++ni) {                    \
      const int r_ = brow0 + ni * 16 + frow;                              \
      BF[ni] = *(const bf16x8*)(lds + 32768 + (P) * 16384 + r_ * 128 + SW8(r_, (H) * 4 + fk)); \
    }                                                                     \
  } while (0)

#define G1_MM(AF, BF)                                                     \
  do {                                                                    \
    __builtin_amdgcn_s_setprio(1);                                        \
    _Pragma("unroll") for (int mi = 0; mi < 4; ++mi)                      \
      _Pragma("unroll") for (int ni = 0; ni < 4; ++ni)                    \
        acc[mi][ni] = __builtin_amdgcn_mfma_f32_16x16x32_bf16(AF[mi], BF[ni], acc[mi][ni], 0, 0, 0); \
    __builtin_amdgcn_s_setprio(0);                                        \
  } while (0)

// one K-tile: reads(h0) -> MFMA -> reads(h1) -> write other buf -> prefetch -> MFMA -> bar
#define G1_STEP(P, QW, DOW, KL)                                           \
  do {                                                                    \
    bf16x8 a0[4], b0[4], a1[4], b1[4];                                    \
    G1_READS(P, 0, a0, b0);                                               \
    G1_MM(a0, b0);                                                        \
    G1_READS(P, 1, a1, b1);                                               \
    if (DOW) G1_WRITE(P ^ 1, QW);                                         \
    if ((KL) < NIT) G1_LOAD(KL, QW);                                      \
    G1_MM(a1, b1);                                                        \
    bar_lgkm();                                                           \
  } while (0)

  const int NIT = HD / 64;  // 16
  G1_LOAD(0, 0);
  G1_LOAD(1, 1);
  G1_WRITE(0, 0);
  bar_lgkm();
  G1_LOAD(2, 0);
  for (int kt = 0; kt < NIT; kt += 2) {
    G1_STEP(0, 1, true, kt + 3);            // compute tile kt, stage kt+1, load kt+3
    G1_STEP(1, 0, (kt + 2 < NIT), kt + 4);  // compute tile kt+1, stage kt+2, load kt+4
  }
#undef G1_LOAD
#undef G1_WRITE
#undef G1_READS
#undef G1_MM
#undef G1_STEP

  // epilogue: gate waves -> f32 LDS exchange [128][68]; up waves fuse gelu(g)*u -> hidden bf16
  __syncthreads();
  float* ex = (float*)lds;
  if (role == 0) {
#pragma unroll
    for (int mi = 0; mi < 4; ++mi)
#pragma unroll
      for (int ni = 0; ni < 4; ++ni)
#pragma unroll
        for (int j = 0; j < 4; ++j) {
          const int row = wrow + mi * 16 + fk * 4 + j;
          ex[row * 68 + ni * 16 + frow] = acc[mi][ni][j];
        }
  }
  __syncthreads();
  if (role == 1) {
#pragma unroll
    for (int mi = 0; mi < 4; ++mi)
#pragma unroll
      for (int j = 0; j < 4; ++j) {
        const int row = wrow + mi * 16 + fk * 4 + j;
        const int grow = mt * 128 + row;
        if (grow < ne) {
          unsigned short* hrow = hidden + (size_t)(off + grow) * ID + nt * 64;
#pragma unroll
          for (int ni = 0; ni < 4; ++ni) {
            const int col = ni * 16 + frow;
            float g = ex[row * 68 + col];
            __bf16 hb = (__bf16)(gelu_tanh(g) * acc[mi][ni][j]);
            hrow[col] = __builtin_bit_cast(unsigned short, hb);
          }
        }
      }
  }
}

// gemm2: out[token] = hidden[p] @ wd[e]^T. BM=128 x BN=128, BK=64, 256 thr / 4 waves
// (2wm x 2wn), wave 64x64. Same 1-barrier-per-tile + depth-2 prefetch structure.
__global__ __launch_bounds__(256, 2) void gemm2_k(
    const unsigned short* __restrict__ hidden, const float* __restrict__ wd,
    const int* __restrict__ perm, const int* __restrict__ counts,
    const int* __restrict__ offsets, const int* __restrict__ tilemap,
    const int* __restrict__ ntiles, float* __restrict__ out) {
  const int t = blockIdx.x >> 3;
  const int nt = blockIdx.x & 7;           // siblings bid+=8 -> same XCD
  if (t >= *ntiles) return;
  const int tm = tilemap[t];
  const int e = tm >> 8, mt = tm & 255;
  const int ne = counts[e];
  const int off = offsets[e];

  __shared__ __align__(16) char lds[65536];  // A: p*16384; B: 32768 + p*16384

  const int tid = threadIdx.x;
  const int lane = tid & 63;
  const int wid = tid >> 6;
  const int wm = wid >> 1, wn = wid & 1;
  const int wrow = wm * 64, wcol = wn * 64;
  const int frow = lane & 15;
  const int fk = lane >> 4;

  // A staging: 2 thr/row, 32 bf16 (64B). row=tid>>1, half=tid&1
  const int ar = tid >> 1, ah = tid & 1;
  int lrA = mt * 128 + ar;
  const unsigned short* asrc = hidden + (size_t)(off + ((lrA < ne) ? lrA : (ne - 1))) * ID + ah * 32;

  // B staging: 2 thr/row, 32 fp32 (128B). row=tid>>1 (out-col nt*128+row)
  const float* bsrc = wd + ((size_t)e * HD + nt * 128 + ar) * ID + ah * 32;

  f32x4 acc[4][4] = {};
  u16x8 rA[2][4];
  f32x4 rB[2][8];

#define G2_LOAD(kt, q)                                                    \
  do {                                                                    \
    const unsigned short* a_ = asrc + (kt) * 64;                          \
    _Pragma("unroll") for (int i = 0; i < 4; ++i)                         \
      rA[q][i] = *(const u16x8*)(a_ + i * 8);                             \
    const float* b_ = bsrc + (kt) * 64;                                   \
    _Pragma("unroll") for (int i = 0; i < 8; ++i)                         \
      rB[q][i] = *(const f32x4*)(b_ + i * 4);                             \
  } while (0)

#define G2_WRITE(P, q)                                                    \
  do {                                                                    \
    _Pragma("unroll") for (int i = 0; i < 4; ++i)                         \
      *(u16x8*)(lds + (P) * 16384 + ar * 128 + SW8(ar, ah * 4 + i)) = rA[q][i]; \
    _Pragma("unroll") for (int i = 0; i < 4; ++i)                         \
      *(bf16x8*)(lds + 32768 + (P) * 16384 + ar * 128 + SW8(ar, ah * 4 + i)) = \
          pack8(rB[q][2 * i], rB[q][2 * i + 1]);                          \
  } while (0)

#define G2_READS(P, H, AF, BF)                                            \
  do {                                                                    \
    _Pragma("unroll") for (int mi = 0; mi < 4; ++mi) {                    \
      const int r_ = wrow + mi * 16 + frow;                               \
      AF[mi] = *(const bf16x8*)(lds + (P) * 16384 + r_ * 128 + SW8(r_, (H) * 4 + fk)); \
    }                                                                     \
    _Pragma("unroll") for (int ni = 0; ni < 4; ++ni) {                    \
      const int r_ = wcol + ni * 16 + frow;                               \
      BF[ni] = *(const bf16x8*)(lds + 32768 + (P) * 16384 + r_ * 128 + SW8(r_, (H) * 4 + fk)); \
    }                                                                     \
  } while (0)

#define G2_MM(AF, BF)                                                     \
  do {                                                                    \
    __builtin_amdgcn_s_setprio(1);                                        \
    _Pragma("unroll") for (int mi = 0; mi < 4; ++mi)                      \
      _Pragma("unroll") for (int ni = 0; ni < 4; ++ni)                    \
        acc[mi][ni] = __builtin_amdgcn_mfma_f32_16x16x32_bf16(AF[mi], BF[ni], acc[mi][ni], 0, 0, 0); \
    __builtin_amdgcn_s_setprio(0);                                        \
  } while (0)

#define G2_STEP(P, QW, DOW, KL)                                           \
  do {                                                                    \
    bf16x8 a0[4], b0[4], a1[4], b1[4];                                    \
    G2_READS(P, 0, a0, b0);                                               \
    G2_MM(a0, b0);                                                        \
    G2_READS(P, 1, a1, b1);                                               \
    if (DOW) G2_WRITE(P ^ 1, QW);                                         \
    if ((KL) < NIT) G2_LOAD(KL, QW);                                      \
    G2_MM(a1, b1);                                                        \
    bar_lgkm();                                                           \
  } while (0)

  const int NIT = ID / 64;  // 64
  G2_LOAD(0, 0);
  G2_LOAD(1, 1);
  G2_WRITE(0, 0);
  bar_lgkm();
  G2_LOAD(2, 0);
  for (int kt = 0; kt < NIT; kt += 2) {
    G2_STEP(0, 1, true, kt + 3);
    G2_STEP(1, 0, (kt + 2 < NIT), kt + 4);
  }
#undef G2_LOAD
#undef G2_WRITE
#undef G2_READS
#undef G2_MM
#undef G2_STEP

#pragma unroll
  for (int mi = 0; mi < 4; ++mi)
#pragma unroll
    for (int j = 0; j < 4; ++j) {
      const int row = wrow + mi * 16 + fk * 4 + j;
      const int grow = mt * 128 + row;
      if (grow < ne) {
        const int tk = perm[off + grow];
        float* orow = out + (size_t)tk * HD + nt * 128 + wcol;
#pragma unroll
        for (int ni = 0; ni < 4; ++ni) orow[ni * 16 + frow] = acc[mi][ni][j];
      }
    }
}

extern "C" void kernel_launch(void* const* d_in, const int* in_sizes, int n_in,
                              void* d_out, int out_size, void* d_ws, size_t ws_size,
                              hipStream_t stream) {
  const float* x  = (const float*)d_in[0];
  const float* gw = (const float*)d_in[1];
  const float* wg = (const float*)d_in[2];
  const float* wu = (const float*)d_in[3];
  const float* wd = (const float*)d_in[4];
  float* out = (float*)d_out;
  float* logits = out + (size_t)TOK * HD;

  unsigned short* hidden = (unsigned short*)d_ws;                       // 33.55 MB
  unsigned short* xp = (unsigned short*)((char*)d_ws + 33554432);       // 8.39 MB
  int* meta = (int*)((char*)d_ws + 33554432 + 8388608);
  int* counts  = meta;             // [8]
  int* counts2 = meta + 8;         // [8]
  int* offsets = meta + 16;        // [8]
  int* tilemap = meta + 24;        // [MAXT]
  int* ntiles  = meta + 24 + MAXT; // [1]
  int* top1    = meta + 72;        // [TOK]
  int* perm    = meta + 72 + TOK;  // [TOK]

  init_k<<<1, 64, 0, stream>>>(meta);
  router_k<<<TOK / 4, 256, 0, stream>>>(x, gw, logits, top1);
  hist_k<<<TOK / 256, 256, 0, stream>>>(top1, counts);
  offsets_k<<<1, 64, 0, stream>>>(counts, offsets, tilemap, ntiles);
  scatter_k<<<TOK / 256, 256, 0, stream>>>(top1, offsets, counts2, perm);
  xp_k<<<TOK / 4, 256, 0, stream>>>(x, perm, xp);
  gemm1_k<<<MAXT * 64, 256, 0, stream>>>(xp, wg, wu, counts, offsets, tilemap, ntiles, hidden);
  gemm2_k<<<MAXT * 8, 256, 0, stream>>>(hidden, wd, perm, counts, offsets, tilemap, ntiles, out);
}

// Round 15
// 314.296 us; speedup vs baseline: 1.3991x; 1.3991x over previous
//
#include <hip/hip_runtime.h>

#define TOK 4096
#define HD 1024
#define ID 4096
#define NE 8
#define MAXT 40   // max m-tiles: sum ceil(ne/128) <= 32 + 8

typedef __attribute__((ext_vector_type(4))) float f32x4;
typedef __attribute__((ext_vector_type(8))) __bf16 bf16x8;

typedef const __attribute__((address_space(1))) void* gas1_t;
typedef __attribute__((address_space(3))) void* las3_t;

// async global->LDS DMA, 16B/lane. LDS dest = wave-uniform base + lane*16 (linear).
// Swizzle is applied on the per-lane GLOBAL source address (m173 pattern).
__device__ __forceinline__ void dma16(const void* g, void* l) {
  __builtin_amdgcn_global_load_lds((gas1_t)g, (las3_t)l, 16, 0, 0);
}

// compiler emits v_cvt_pk_bf16_f32 (RNE) for scalar casts -- do NOT hand-roll (m240)
__device__ __forceinline__ bf16x8 pack8(f32x4 a, f32x4 b) {
  bf16x8 r;
#pragma unroll
  for (int i = 0; i < 4; ++i) { r[i] = (__bf16)a[i]; r[i + 4] = (__bf16)b[i]; }
  return r;
}

__device__ __forceinline__ float gelu_tanh(float g) {
  float z = 0.7978845608028654f * (g + 0.044715f * g * g * g);
  float t = __expf(-2.0f * z);
  return g / (1.0f + t);
}

// barrier that does NOT drain vmcnt
__device__ __forceinline__ void bar_lgkm() {
  asm volatile("s_waitcnt lgkmcnt(0)" ::: "memory");
  __builtin_amdgcn_s_barrier();
}
__device__ __forceinline__ void wait_vm0() {
  asm volatile("s_waitcnt vmcnt(0)" ::: "memory");
}

__global__ void init_k(int* __restrict__ meta) {
  if (threadIdx.x < 16) meta[threadIdx.x] = 0;
}

// one wave per token: fp32 logits (argmax must match numpy fp32), top1 via first-max
__global__ void router_k(const float* __restrict__ x, const float* __restrict__ gw,
                         float* __restrict__ logits, int* __restrict__ top1) {
  const int wid = threadIdx.x >> 6;
  const int lane = threadIdx.x & 63;
  const int t = blockIdx.x * 4 + wid;
  const float* xr = x + (size_t)t * HD;
  float acc[NE];
#pragma unroll
  for (int e = 0; e < NE; ++e) acc[e] = 0.0f;
#pragma unroll
  for (int c = 0; c < 4; ++c) {
    const int k = (c * 64 + lane) * 4;
    f32x4 xv = *(const f32x4*)(xr + k);
#pragma unroll
    for (int e = 0; e < NE; ++e) {
      f32x4 gv = *(const f32x4*)(gw + e * HD + k);
      acc[e] += xv[0] * gv[0] + xv[1] * gv[1] + xv[2] * gv[2] + xv[3] * gv[3];
    }
  }
#pragma unroll
  for (int off = 32; off > 0; off >>= 1) {
#pragma unroll
    for (int e = 0; e < NE; ++e) acc[e] += __shfl_xor(acc[e], off, 64);
  }
  if (lane == 0) {
    int best = 0; float bv = acc[0];
#pragma unroll
    for (int e = 1; e < NE; ++e) if (acc[e] > bv) { bv = acc[e]; best = e; }
    top1[t] = best;
#pragma unroll
    for (int e = 0; e < NE; ++e) logits[(size_t)t * NE + e] = acc[e];
  }
}

__global__ void hist_k(const int* __restrict__ top1, int* __restrict__ counts) {
  int t = blockIdx.x * 256 + threadIdx.x;
  atomicAdd(&counts[top1[t]], 1);
}

__global__ void offsets_k(const int* __restrict__ counts, int* __restrict__ offsets,
                          int* __restrict__ tilemap, int* __restrict__ ntiles) {
  if (threadIdx.x == 0) {
    int s = 0;
    for (int e = 0; e < NE; ++e) { offsets[e] = s; s += counts[e]; }
    int t = 0;
    for (int e = 0; e < NE; ++e) {
      int nt_e = (counts[e] + 127) >> 7;
      for (int i = 0; i < nt_e; ++i) tilemap[t++] = (e << 8) | i;
    }
    *ntiles = t;
  }
}

__global__ void scatter_k(const int* __restrict__ top1, const int* __restrict__ offsets,
                          int* __restrict__ counts2, int* __restrict__ perm) {
  int t = blockIdx.x * 256 + threadIdx.x;
  int e = top1[t];
  int slot = atomicAdd(&counts2[e], 1);
  perm[offsets[e] + slot] = t;
}

// compact permuted bf16 copy of x: xp[p,:] = bf16(x[perm[p],:])
__global__ void xp_k(const float* __restrict__ x, const int* __restrict__ perm,
                     unsigned short* __restrict__ xp) {
  const int p = blockIdx.x * 4 + (threadIdx.x >> 6);
  const int lane = threadIdx.x & 63;
  const float* src = x + (size_t)perm[p] * HD + lane * 16;
  unsigned short* dst = xp + (size_t)p * HD + lane * 16;
  f32x4 v0 = *(const f32x4*)(src);
  f32x4 v1 = *(const f32x4*)(src + 4);
  f32x4 v2 = *(const f32x4*)(src + 8);
  f32x4 v3 = *(const f32x4*)(src + 12);
  *(bf16x8*)(dst) = pack8(v0, v1);
  *(bf16x8*)(dst + 8) = pack8(v2, v3);
}

// gemm1: BM=128 tok x (64 gate || 64 up cols of panel nt), BK=32, 256 thr / 4 waves
// (2wm x 2role), wave 64x64, acc 4x4. ALL staging via global_load_lds DMA:
// A = xp bf16 (8KB/tile, 2 instr/wave), B = weights STAGED AS FP32 (16KB/tile,
// 4 instr/wave), cvt to bf16 at LDS-read (4 cvt_pk/frag, co-issues with MFMA).
// Swizzle on global source; LDS linear. dbuf; vmcnt(0) covered by compute; lgkm barrier.
__global__ __launch_bounds__(256, 3) void gemm1_k(
    const unsigned short* __restrict__ xp, const float* __restrict__ wg,
    const float* __restrict__ wu, const int* __restrict__ counts,
    const int* __restrict__ offsets, const int* __restrict__ tilemap,
    const int* __restrict__ ntiles, unsigned short* __restrict__ hidden) {
  const int t = blockIdx.x >> 6;
  const int nt = blockIdx.x & 63;          // mt-siblings: bid += 64 -> same XCD
  if (t >= *ntiles) return;
  const int tm = tilemap[t];
  const int e = tm >> 8, mt = tm & 255;
  const int ne = counts[e];
  const int off = offsets[e];

  __shared__ __align__(16) char lds[49152];  // A: p*8192 (bf16); B: 16384 + p*16384 (fp32)

  const int tid = threadIdx.x;
  const int lane = tid & 63;
  const int wid = tid >> 6;
  const int wm = wid >> 1;                 // rows wm*64
  const int role = wid & 1;                // 0 = gate, 1 = up
  const int wrow = wm * 64;
  const int frow = lane & 15;
  const int fk = lane >> 4;                // 0..3 k-slot

  // A DMA: instr i in {0,1}: rows wid*32 + i*16 + (lane>>2), phys slot lane&3.
  // global slot = (lane&3) ^ ((row>>1)&3)  [read applies same XOR]
  const char* aSrc[2];
#pragma unroll
  for (int i = 0; i < 2; ++i) {
    const int row = wid * 32 + i * 16 + (lane >> 2);
    int tr = off + mt * 128 + row;
    if (tr >= TOK) tr = TOK - 1;           // masked at store
    const int sA = (lane & 3) ^ ((row >> 1) & 3);
    aSrc[i] = (const char*)xp + (size_t)tr * (HD * 2) + sA * 16;
  }
  // B DMA: instr i in {0..3}: rows wid*32 + i*8 + (lane>>3) (0-63 gate, 64-127 up),
  // phys slot lane&7, global slot = (lane&7) ^ (row&7)
  const char* bSrc[4];
#pragma unroll
  for (int i = 0; i < 4; ++i) {
    const int row = wid * 32 + i * 8 + (lane >> 3);
    const int sB = (lane & 7) ^ (row & 7);
    const float* base = (row < 64)
        ? wg + ((size_t)e * ID + nt * 64 + row) * HD
        : wu + ((size_t)e * ID + nt * 64 + (row - 64)) * HD;
    bSrc[i] = (const char*)base + sB * 16;
  }

  f32x4 acc[4][4] = {};

#define G1_ISSUE(kt, P)                                                   \
  do {                                                                    \
    _Pragma("unroll") for (int i = 0; i < 2; ++i)                         \
      dma16(aSrc[i] + (kt) * 64, lds + (P) * 8192 + wid * 2048 + i * 1024); \
    _Pragma("unroll") for (int i = 0; i < 4; ++i)                         \
      dma16(bSrc[i] + (kt) * 128, lds + 16384 + (P) * 16384 + wid * 4096 + i * 1024); \
  } while (0)

#define G1_COMP(P)                                                        \
  do {                                                                    \
    bf16x8 af[4], bb[4];                                                  \
    _Pragma("unroll") for (int mi = 0; mi < 4; ++mi) {                    \
      const int r_ = wrow + mi * 16 + frow;                               \
      af[mi] = *(const bf16x8*)(lds + (P) * 8192 + r_ * 64 + ((fk ^ ((r_ >> 1) & 3)) << 4)); \
    }                                                                     \
    _Pragma("unroll") for (int ni = 0; ni < 4; ++ni) {                    \
      const int r_ = role * 64 + ni * 16 + frow;                          \
      f32x4 lo = *(const f32x4*)(lds + 16384 + (P) * 16384 + r_ * 128 + (((2 * fk) ^ (r_ & 7)) << 4)); \
      f32x4 hi = *(const f32x4*)(lds + 16384 + (P) * 16384 + r_ * 128 + (((2 * fk + 1) ^ (r_ & 7)) << 4)); \
      bb[ni] = pack8(lo, hi);                                             \
    }                                                                     \
    __builtin_amdgcn_s_setprio(1);                                        \
    _Pragma("unroll") for (int mi = 0; mi < 4; ++mi)                      \
      _Pragma("unroll") for (int ni = 0; ni < 4; ++ni)                    \
        acc[mi][ni] = __builtin_amdgcn_mfma_f32_16x16x32_bf16(af[mi], bb[ni], acc[mi][ni], 0, 0, 0); \
    __builtin_amdgcn_s_setprio(0);                                        \
  } while (0)

  const int NIT = HD / 32;  // 32
  G1_ISSUE(0, 0);
  wait_vm0();
  __builtin_amdgcn_s_barrier();
  for (int kt = 0; kt < NIT; kt += 2) {
    G1_ISSUE(kt + 1, 1);
    G1_COMP(0);
    wait_vm0();
    bar_lgkm();
    if (kt + 2 < NIT) G1_ISSUE(kt + 2, 0);
    G1_COMP(1);
    if (kt + 2 < NIT) wait_vm0();
    bar_lgkm();
  }
#undef G1_ISSUE
#undef G1_COMP

  // epilogue: gate waves -> f32 LDS exchange [128][68]; up waves fuse gelu(g)*u -> bf16
  __syncthreads();
  float* ex = (float*)lds;
  if (role == 0) {
#pragma unroll
    for (int mi = 0; mi < 4; ++mi)
#pragma unroll
      for (int ni = 0; ni < 4; ++ni)
#pragma unroll
        for (int j = 0; j < 4; ++j) {
          const int row = wrow + mi * 16 + fk * 4 + j;
          ex[row * 68 + ni * 16 + frow] = acc[mi][ni][j];
        }
  }
  __syncthreads();
  if (role == 1) {
#pragma unroll
    for (int mi = 0; mi < 4; ++mi)
#pragma unroll
      for (int j = 0; j < 4; ++j) {
        const int row = wrow + mi * 16 + fk * 4 + j;
        const int grow = mt * 128 + row;
        if (grow < ne) {
          unsigned short* hrow = hidden + (size_t)(off + grow) * ID + nt * 64;
#pragma unroll
          for (int ni = 0; ni < 4; ++ni) {
            const int col = ni * 16 + frow;
            float g = ex[row * 68 + col];
            __bf16 hb = (__bf16)(gelu_tanh(g) * acc[mi][ni][j]);
            hrow[col] = __builtin_bit_cast(unsigned short, hb);
          }
        }
      }
  }
}

// gemm2: out[token] = hidden[p] @ wd[e]^T. BM=128 x BN=128, BK=32, 256 thr / 4 waves
// (2wm x 2wn), wave 64x64. Same DMA-staged dbuf structure; B = wd fp32 in LDS.
__global__ __launch_bounds__(256, 3) void gemm2_k(
    const unsigned short* __restrict__ hidden, const float* __restrict__ wd,
    const int* __restrict__ perm, const int* __restrict__ counts,
    const int* __restrict__ offsets, const int* __restrict__ tilemap,
    const int* __restrict__ ntiles, float* __restrict__ out) {
  const int t = blockIdx.x >> 3;
  const int nt = blockIdx.x & 7;           // mt-siblings: bid += 8 -> same XCD
  if (t >= *ntiles) return;
  const int tm = tilemap[t];
  const int e = tm >> 8, mt = tm & 255;
  const int ne = counts[e];
  const int off = offsets[e];

  __shared__ __align__(16) char lds[49152];  // A: p*8192 (bf16); B: 16384 + p*16384 (fp32)

  const int tid = threadIdx.x;
  const int lane = tid & 63;
  const int wid = tid >> 6;
  const int wm = wid >> 1, wn = wid & 1;
  const int wrow = wm * 64, wcol = wn * 64;
  const int frow = lane & 15;
  const int fk = lane >> 4;

  const char* aSrc[2];
#pragma unroll
  for (int i = 0; i < 2; ++i) {
    const int row = wid * 32 + i * 16 + (lane >> 2);
    int lr = mt * 128 + row;
    const int gr = off + ((lr < ne) ? lr : (ne - 1));
    const int sA = (lane & 3) ^ ((row >> 1) & 3);
    aSrc[i] = (const char*)hidden + (size_t)gr * (ID * 2) + sA * 16;
  }
  const char* bSrc[4];
#pragma unroll
  for (int i = 0; i < 4; ++i) {
    const int row = wid * 32 + i * 8 + (lane >> 3);
    const int sB = (lane & 7) ^ (row & 7);
    bSrc[i] = (const char*)(wd + ((size_t)e * HD + nt * 128 + row) * ID) + sB * 16;
  }

  f32x4 acc[4][4] = {};

#define G2_ISSUE(kt, P)                                                   \
  do {                                                                    \
    _Pragma("unroll") for (int i = 0; i < 2; ++i)                         \
      dma16(aSrc[i] + (kt) * 64, lds + (P) * 8192 + wid * 2048 + i * 1024); \
    _Pragma("unroll") for (int i = 0; i < 4; ++i)                         \
      dma16(bSrc[i] + (kt) * 128, lds + 16384 + (P) * 16384 + wid * 4096 + i * 1024); \
  } while (0)

#define G2_COMP(P)                                                        \
  do {                                                                    \
    bf16x8 af[4], bb[4];                                                  \
    _Pragma("unroll") for (int mi = 0; mi < 4; ++mi) {                    \
      const int r_ = wrow + mi * 16 + frow;                               \
      af[mi] = *(const bf16x8*)(lds + (P) * 8192 + r_ * 64 + ((fk ^ ((r_ >> 1) & 3)) << 4)); \
    }                                                                     \
    _Pragma("unroll") for (int ni = 0; ni < 4; ++ni) {                    \
      const int r_ = wcol + ni * 16 + frow;                               \
      f32x4 lo = *(const f32x4*)(lds + 16384 + (P) * 16384 + r_ * 128 + (((2 * fk) ^ (r_ & 7)) << 4)); \
      f32x4 hi = *(const f32x4*)(lds + 16384 + (P) * 16384 + r_ * 128 + (((2 * fk + 1) ^ (r_ & 7)) << 4)); \
      bb[ni] = pack8(lo, hi);                                             \
    }                                                                     \
    __builtin_amdgcn_s_setprio(1);                                        \
    _Pragma("unroll") for (int mi = 0; mi < 4; ++mi)                      \
      _Pragma("unroll") for (int ni = 0; ni < 4; ++ni)                    \
        acc[mi][ni] = __builtin_amdgcn_mfma_f32_16x16x32_bf16(af[mi], bb[ni], acc[mi][ni], 0, 0, 0); \
    __builtin_amdgcn_s_setprio(0);                                        \
  } while (0)

  const int NIT = ID / 32;  // 128
  G2_ISSUE(0, 0);
  wait_vm0();
  __builtin_amdgcn_s_barrier();
  for (int kt = 0; kt < NIT; kt += 2) {
    G2_ISSUE(kt + 1, 1);
    G2_COMP(0);
    wait_vm0();
    bar_lgkm();
    if (kt + 2 < NIT) G2_ISSUE(kt + 2, 0);
    G2_COMP(1);
    if (kt + 2 < NIT) wait_vm0();
    bar_lgkm();
  }
#undef G2_ISSUE
#undef G2_COMP

#pragma unroll
  for (int mi = 0; mi < 4; ++mi)
#pragma unroll
    for (int j = 0; j < 4; ++j) {
      const int row = wrow + mi * 16 + fk * 4 + j;
      const int grow = mt * 128 + row;
      if (grow < ne) {
        const int tk = perm[off + grow];
        float* orow = out + (size_t)tk * HD + nt * 128 + wcol;
#pragma unroll
        for (int ni = 0; ni < 4; ++ni) orow[ni * 16 + frow] = acc[mi][ni][j];
      }
    }
}

extern "C" void kernel_launch(void* const* d_in, const int* in_sizes, int n_in,
                              void* d_out, int out_size, void* d_ws, size_t ws_size,
                              hipStream_t stream) {
  const float* x  = (const float*)d_in[0];
  const float* gw = (const float*)d_in[1];
  const float* wg = (const float*)d_in[2];
  const float* wu = (const float*)d_in[3];
  const float* wd = (const float*)d_in[4];
  float* out = (float*)d_out;
  float* logits = out + (size_t)TOK * HD;

  unsigned short* hidden = (unsigned short*)d_ws;                       // 33.55 MB
  unsigned short* xp = (unsigned short*)((char*)d_ws + 33554432);       // 8.39 MB
  int* meta = (int*)((char*)d_ws + 33554432 + 8388608);
  int* counts  = meta;             // [8]
  int* counts2 = meta + 8;         // [8]
  int* offsets = meta + 16;        // [8]
  int* tilemap = meta + 24;        // [MAXT]
  int* ntiles  = meta + 24 + MAXT; // [1]
  int* top1    = meta + 72;        // [TOK]
  int* perm    = meta + 72 + TOK;  // [TOK]

  init_k<<<1, 64, 0, stream>>>(meta);
  router_k<<<TOK / 4, 256, 0, stream>>>(x, gw, logits, top1);
  hist_k<<<TOK / 256, 256, 0, stream>>>(top1, counts);
  offsets_k<<<1, 64, 0, stream>>>(counts, offsets, tilemap, ntiles);
  scatter_k<<<TOK / 256, 256, 0, stream>>>(top1, offsets, counts2, perm);
  xp_k<<<TOK / 4, 256, 0, stream>>>(x, perm, xp);
  gemm1_k<<<MAXT * 64, 256, 0, stream>>>(xp, wg, wu, counts, offsets, tilemap, ntiles, hidden);
  gemm2_k<<<MAXT * 8, 256, 0, stream>>>(hidden, wd, perm, counts, offsets, tilemap, ntiles, out);
}